// Round 9
// baseline (1054.618 us; speedup 1.0000x reference)
//
#include <hip/hip_runtime.h>
#include <hip/hip_bf16.h>

// GCLSTM: B=512, T=32, H=300, K=10. f32 in/out.
// R9 = R7 (scalar cells — R8's MFMA-cells regressed) + t-loop blocks:
// grid (128 bt, 4 tg), 8 t per block; con halves ping-pong in cct by parity
// (c0=304*(t&1) holds con_t, other half holds con_{t-1}); cells computed
// once per t (not twice); wp A-frag tables per parity. F1 GEMM split:
// con-part (K=300, b1 via f32 acc init) + ht-part (M=4 GEMM, shfl broadcast);
// no zero-init / bias cols needed (all garbage lanes hit B=0).

#define TB 4
#define NTHR 640          // 10 waves
#define NW 10
#define KP 616

// ws layout (u32 slots)
#define OFF_SM    0         // softmax [32][10][512] f32            163840
#define OFF_WPA   163840    // wp A-frags [p2][mt19][ks19][lane][4]  184832
#define OFF_F1C   348672    // F1 con-part B-frags [nt13][ks10][lane][4] 33280
#define OFF_F1H   381952    // F1 ht-part  B-frags [nt13][ks10][lane][4] 33280
#define OFF_WIHP  415232    // ((k*11+i)*3+g)*300+h f32              99000
#define OFF_BCP   514232    // (k*3+g)*300+h f32                      9000
#define OFF_BTP   523232    // g*300+h f32                             900
#define OFF_WTP   524132    // (e*3+g)*300+h f32                      3600
#define OFF_WA    527732    // softmax(DisM) f32                        10
#define OFF_SWA   527742    // sum(wA) f32                               1
#define BASE_U32  527744
#define CON1_BYTE ((size_t)BASE_U32 * 4)                  // 2,110,976
#define WS_MIN_BYTES (CON1_BYTE + (size_t)98304000)       // 100,414,976 (< proven 100,436,608)

typedef __attribute__((ext_vector_type(8))) short s16x8;
typedef __attribute__((ext_vector_type(4))) float f32x4;
typedef unsigned short u16;

__device__ __forceinline__ float sigf(float x){ return 1.0f/(1.0f+__expf(-x)); }
__device__ __forceinline__ float tanhf_(float x){ return 1.0f - 2.0f/(__expf(2.0f*x)+1.0f); }
__device__ __forceinline__ float bfu(u16 u){ return __uint_as_float(((unsigned)u)<<16); }
__device__ __forceinline__ u16 f2us(float f){ return (u16)(__float_as_uint(f)>>16); }
__device__ __forceinline__ u16 f2usr(float f){   // RNE bf16
  __hip_bfloat16 h = __float2bfloat16(f);
  return *(u16*)&h;
}

// ================= per-(b-tile, t-group) kernel: loops 8 timesteps =================
__global__ __launch_bounds__(NTHR,2) void kern_main(
    const float* __restrict__ li, const float* __restrict__ exs,
    const float* __restrict__ AngleM, const float* __restrict__ bp,
    const float* __restrict__ F2, const float* __restrict__ b2,
    const float* __restrict__ b1, const float* wsf,
    unsigned* __restrict__ con1u, float* smg)
{
  __shared__ __align__(16) u16 cct[48][KP];          // 59,136
  __shared__ __align__(16) float xs[2][TB][11][10];  //  3,520
  __shared__ __align__(16) u16 hts[4][304];          //  2,432
  __shared__ u16 xseh[TB][2][10];                    //    160
  __shared__ float wdL[48];                          //    192  (total 65,440)
  const int tid = threadIdx.x;
  const int bt = blockIdx.x, tg = blockIdx.y, b0 = bt*TB;
  const int w = tid>>6, lane = tid&63, lo = lane&15, qd = lane>>4;

  // hoisted per-wave constants (F2 cols + b1 for this wave's nt tiles)
  float f2c[2], b1v[2];
  #pragma unroll
  for (int j=0;j<2;j++){
    int nt = w + j*NW, col = nt*16+lo;
    bool val = (nt<13) && (col<200);
    f2c[j] = val ? F2[col] : 0.f;
    b1v[j] = val ? b1[col] : 0.f;
  }

  for (int ti=0; ti<8; ti++){
    const int t = tg*8+ti;
    const int p = t&1;
    const int c0 = 304*p, c1 = 304-c0;
    const int cc1 = (t==0) ? c0 : c1;    // where con1^T lives for this t
    __syncthreads();   // prev-iter readers of xs/xseh/wdL/cct/hts are done

    // ---- P0: stage x (cur; +prev at ti==0), xse, zero wdL ----
    {
      const int tot = (ti==0 && t>0) ? 880 : 440;
      for (int pp=tid; pp<tot; pp+=NTHR){
        int hf=pp/440, r=pp%440, b=r/110, q=r%110, i=q/10, k=q%10;
        xs[hf? (1-p):p][b][i][k] = li[(((b0+b)*32 + (hf? t-1:t))*28 + i)*10 + k];
      }
      for (int pp=tid; pp<TB*20; pp+=NTHR){
        int b=pp/20, r=pp%20, rr=r/10, k=r%10;
        xseh[b][rr][k] = f2usr(li[(((b0+b)*32+t)*28 + (rr?10:8))*10 + k]);
      }
      if (tid<48) wdL[tid]=0.f;
    }
    __syncthreads();

    // ---- P1: scalar cells for t (and t-1 if ti==0) -> cct halves ----
    {
      const int tot = (ti==0 && t>0) ? 6000 : 3000;
      for (int pt=tid; pt<tot; pt+=NTHR){
        int hf=pt/3000, q=pt%3000, k=q/300, h=q%300;
        const float* W = wsf + OFF_WIHP + k*9900 + h;
        float wi[11], wg[11], wo[11];
        #pragma unroll
        for (int i=0;i<11;i++){
          wi[i]=W[(i*3+0)*300]; wg[i]=W[(i*3+1)*300]; wo[i]=W[(i*3+2)*300];
        }
        float bi = wsf[OFF_BCP+(k*3+0)*300+h];
        float bg2= wsf[OFF_BCP+(k*3+1)*300+h];
        float bo = wsf[OFF_BCP+(k*3+2)*300+h];
        const int xi = hf? (1-p):p;
        const int cb = hf? c1 : c0;
        #pragma unroll
        for (int b=0;b<TB;b++){
          float ai=0.f, ag=0.f, ao=0.f;
          #pragma unroll
          for (int i=0;i<11;i++){
            float xv = xs[xi][b][i][k];
            ai += wi[i]*xv; ag += wg[i]*xv; ao += wo[i]*xv;
          }
          float hv = sigf(ao+bo) * tanhf_( sigf(ai+bi) * tanhf_(ag+bg2) );
          cct[b*10+k][cb+h] = f2usr(hv);
        }
      }
    }
    __syncthreads();

    // ---- P2: wp-MFMA D[o 304][n 48] over K=608 (both halves); 2 Mtiles/wave ----
    f32x4 acc[2][3];
    #pragma unroll
    for (int i=0;i<2;i++)
      #pragma unroll
      for (int nt=0;nt<3;nt++) acc[i][nt] = (f32x4){0.f,0.f,0.f,0.f};
    if (t>0){
      const u16* wA = (const u16*)((const unsigned*)wsf + OFF_WPA + (size_t)p*92416);
      for (int ks=0; ks<19; ks++){
        const int kb = ks*32 + qd*8;
        s16x8 Bv[3];
        #pragma unroll
        for (int nt=0;nt<3;nt++)
          Bv[nt] = *(const s16x8*)&cct[nt*16+lo][kb];
        #pragma unroll
        for (int i=0;i<2;i++){
          int mt = w*2+i;
          if (mt<19){
            s16x8 Av = *(const s16x8*)(wA + ((size_t)(mt*19+ks)*64 + lane)*8);
            #pragma unroll
            for (int nt=0;nt<3;nt++)
              acc[i][nt] = __builtin_amdgcn_mfma_f32_16x16x32_bf16(Av, Bv[nt], acc[i][nt], 0,0,0);
          }
        }
      }
    }
    __syncthreads();   // all B reads done before overwriting the dead half

    // ---- P2b (t>0): epilogue transpose con1^T -> cols [c1..c1+300) ----
    if (t>0){
      #pragma unroll
      for (int i=0;i<2;i++){
        int mt = w*2+i;
        if (mt<19 && (mt<18 || qd<3)){   // skip o in [300,304)
          int ob = mt*16 + qd*4;
          float p0=bp[ob], p1=bp[ob+1], p2=bp[ob+2], p3=bp[ob+3];
          #pragma unroll
          for (int nt=0;nt<3;nt++){
            int n = nt*16+lo;
            float v0=acc[i][nt][0]+p0, v1=acc[i][nt][1]+p1,
                  v2=acc[i][nt][2]+p2, v3=acc[i][nt][3]+p3;
            unsigned w0 = ((unsigned)f2us(v1>0.f?v1:0.f)<<16) | f2us(v0>0.f?v0:0.f);
            unsigned w1 = ((unsigned)f2us(v3>0.f?v3:0.f)<<16) | f2us(v2>0.f?v2:0.f);
            *(unsigned*)&cct[n][c1+ob]   = w0;
            *(unsigned*)&cct[n][c1+ob+2] = w1;
          }
        }
      }
    }
    // ---- P3: htarget -> hts[4][300] (no replication) ----
    for (int pt=tid; pt<1200; pt+=NTHR){
      int b=pt/300, o=pt%300;
      float e0=exs[((b0+b)*32+t)*4+0], e1=exs[((b0+b)*32+t)*4+1],
            e2=exs[((b0+b)*32+t)*4+2], e3=exs[((b0+b)*32+t)*4+3];
      float ai = wsf[OFF_WTP+0*300+o]*e0 + wsf[OFF_WTP+3*300+o]*e1
               + wsf[OFF_WTP+6*300+o]*e2 + wsf[OFF_WTP+9*300+o]*e3 + wsf[OFF_BTP+o];
      float ag = wsf[OFF_WTP+1*300+o]*e0 + wsf[OFF_WTP+4*300+o]*e1
               + wsf[OFF_WTP+7*300+o]*e2 + wsf[OFF_WTP+10*300+o]*e3 + wsf[OFF_BTP+300+o];
      float ao = wsf[OFF_WTP+2*300+o]*e0 + wsf[OFF_WTP+5*300+o]*e1
               + wsf[OFF_WTP+8*300+o]*e2 + wsf[OFF_WTP+11*300+o]*e3 + wsf[OFF_BTP+600+o];
      hts[b][o] = f2usr( sigf(ao)*tanhf_(sigf(ai)*tanhf_(ag)) );
    }
    __syncthreads();

    // ---- P5: store con1 tile [n 40][o 300] ----
    for (int pp=tid; pp<6000; pp+=NTHR){
      int n=pp/150, op=pp%150;
      con1u[ ((size_t)(t*128+bt)*40 + n)*150 + op ] = *(const unsigned*)&cct[n][cc1+2*op];
    }

    // ---- P4a: F1 con-part MFMA  (K=300+pad, b1 in acc init) ----
    f32x4 acc2[3][2];
    #pragma unroll
    for (int mt=0;mt<3;mt++)
      #pragma unroll
      for (int j=0;j<2;j++) acc2[mt][j] = (f32x4){b1v[j],b1v[j],b1v[j],b1v[j]};
    {
      const u16* f1c = (const u16*)((const unsigned*)wsf + OFF_F1C);
      for (int ks=0; ks<10; ks++){
        const int kb = cc1 + ks*32 + qd*8;
        s16x8 Am[3];
        #pragma unroll
        for (int mt=0;mt<3;mt++)
          Am[mt] = *(const s16x8*)&cct[mt*16+lo][kb];
        #pragma unroll
        for (int j=0;j<2;j++){
          int nt = w + j*NW;
          if (nt<13){
            s16x8 Bf = *(const s16x8*)(f1c + ((size_t)(nt*10+ks)*64 + lane)*8);
            #pragma unroll
            for (int mt=0;mt<3;mt++)
              acc2[mt][j] = __builtin_amdgcn_mfma_f32_16x16x32_bf16(Am[mt], Bf, acc2[mt][j], 0,0,0);
          }
        }
      }
    }
    // ---- P4b: F1 ht-part MFMA (M=4 tile), broadcast via shfl ----
    f32x4 htD[2];
    #pragma unroll
    for (int j=0;j<2;j++) htD[j] = (f32x4){0.f,0.f,0.f,0.f};
    {
      const u16* f1h = (const u16*)((const unsigned*)wsf + OFF_F1H);
      for (int ks=0; ks<10; ks++){
        const int kb = ks*32 + qd*8;
        s16x8 Ah = (s16x8){0,0,0,0,0,0,0,0};
        if (lo<4) Ah = *(const s16x8*)&hts[lo][kb];
        #pragma unroll
        for (int j=0;j<2;j++){
          int nt = w + j*NW;
          if (nt<13){
            s16x8 Bh = *(const s16x8*)(f1h + ((size_t)(nt*10+ks)*64 + lane)*8);
            htD[j] = __builtin_amdgcn_mfma_f32_16x16x32_bf16(Ah, Bh, htD[j], 0,0,0);
          }
        }
      }
    }
    float htb[2][4];   // [j][b] = ht-part for col (w/w+10)*16+lo, batch b
    #pragma unroll
    for (int j=0;j<2;j++)
      #pragma unroll
      for (int r=0;r<4;r++) htb[j][r] = __shfl(htD[j][r], lo);
    // ---- wdyn: relu(conpart+htpart)*F2, reduce, atomic into wdL ----
    #pragma unroll
    for (int mt=0;mt<3;mt++)
      #pragma unroll
      for (int r=0;r<4;r++){
        int n = mt*16 + qd*4 + r;
        int bsel = (n<40)? n/10 : 0;
        float s = 0.f;
        #pragma unroll
        for (int j=0;j<2;j++){
          float v = acc2[mt][j][r] + htb[j][bsel];
          v = fmaxf(v, 0.f);
          s += v * f2c[j];
        }
        s += __shfl_xor(s,1,64); s += __shfl_xor(s,2,64);
        s += __shfl_xor(s,4,64); s += __shfl_xor(s,8,64);
        if (lo==0 && n<40) atomicAdd(&wdL[n], s);
      }
    __syncthreads();
    // ---- finalize wdyn ----
    if (tid<40){
      int n=tid, b=n/10, k=n%10;
      float x8 = bfu(xseh[b][0][k]), x10 = bfu(xseh[b][1][k]);
      float ang = fabsf(x10 - AngleM[k]) * (1.0f/360.0f);
      float v = wdL[n] + x8*F2[200] + ang*F2[201] + b2[0];
      wdL[n] = fmaxf(v, 0.f);
    }
    __syncthreads();
    // ---- softmax over k -> smg ----
    if (tid<TB){
      int b=tid;
      float m = wdL[b*10];
      #pragma unroll
      for (int k=1;k<10;k++) m = fmaxf(m, wdL[b*10+k]);
      float e[10]; float s=0.f;
      #pragma unroll
      for (int k=0;k<10;k++){ e[k]=__expf(wdL[b*10+k]-m); s+=e[k]; }
      float inv = 1.0f/s;
      #pragma unroll
      for (int k=0;k<10;k++) smg[t*5120 + k*512 + b0+b] = e[k]*inv;
    }
  }
}

// ================= final: gather scramble, fuse, preds (10 waves) =================
__global__ __launch_bounds__(NTHR,3) void kern_final(
    const float* __restrict__ li, const float* __restrict__ ff,
    const float* __restrict__ bff, const float* __restrict__ fuse1,
    const float* __restrict__ biasf, const float* __restrict__ Wout,
    const float* __restrict__ biasout, const float* __restrict__ a,
    const float* wsf, const unsigned* __restrict__ con1u,
    float* __restrict__ outp)
{
  __shared__ unsigned conTu[40][152];   // [n][o-pairs]; u16 view stride 304
  __shared__ float xs17[TB][17][10];
  __shared__ float cats[TB][300];
  __shared__ float wa3s[TB][10];
  __shared__ float dss[TB][17];
  __shared__ float wAs[10];
  __shared__ float fup1[8][64], fup2[8][64];
  const int tid=threadIdx.x, t=blockIdx.y, bt=blockIdx.x, b0=bt*TB;
  for (int p=tid;p<TB*170;p+=NTHR){
    int b=p/170, r=p%170, f=r/10, k=r%10;
    xs17[b][f][k] = li[(((b0+b)*32+t)*28 + 11+f)*10 + k];
  }
  if (tid<10) wAs[tid] = wsf[OFF_WA+tid];
  for (int p=tid;p<6000;p+=NTHR){
    int n=p/150, op=p%150;
    conTu[n][op] = con1u[ ((size_t)(t*128+bt)*40 + n)*150 + op ];
  }
  __syncthreads();
  for (int p=tid;p<TB*10;p+=NTHR){
    int b=p/10, k=p%10;
    int g = (b0+b)*10+k;   // flat-reshape scramble of the [10,512] softmax matrix
    wa3s[b][k] = wsf[OFF_SM + t*5120 + (g>>9)*512 + (g&511)];
  }
  for (int p=tid;p<TB*17;p+=NTHR){
    int b=p/17, f=p%17; float s=0.f;
    #pragma unroll
    for (int k=0;k<10;k++) s += xs17[b][f][k]*wAs[k];
    dss[b][f]=s;
  }
  __syncthreads();
  const u16* conT = (const u16*)conTu;
  for (int p=tid;p<TB*300;p+=NTHR){
    int b=p/300, h=p%300;
    float s=0.f;
    #pragma unroll
    for (int k=0;k<10;k++)
      s += bfu(conT[(b*10+k)*304 + h]) * wa3s[b][k];
    cats[b][h]=s;
  }
  __syncthreads();
  const int w = tid>>6, lane = tid&63;
  const int o1 = lane;
  const bool o2v = lane<36;
  const int o2 = o2v ? (64+lane) : 99;
  if (w<8){   // fuse1 partials: wave = (b, half of h-range)
    int b=w>>1, half=w&1;
    float fu1 = half? 0.f : biasf[o1];
    float fu2 = half? 0.f : biasf[o2];
    const int hb = half*150;
    for (int h=hb; h<hb+150; h++){
      float cv = cats[b][h];
      fu1 += cv*fuse1[h*100+o1];
      fu2 += cv*fuse1[h*100+o2];
    }
    fup1[w][lane]=fu1; fup2[w][lane]=fu2;
  }
  __syncthreads();
  if (w<TB){
    const int b=w, bg=b0+b;
    const float aa = a[0], swa = wsf[OFF_SWA];
    float fu1 = fup1[2*b][lane] + fup1[2*b+1][lane];
    float fu2 = fup2[2*b][lane] + fup2[2*b+1][lane];
    float fd1 = bff[o1]*swa, fd2 = bff[o2]*swa;
    #pragma unroll
    for (int f=0;f<17;f++){
      float dv = dss[b][f];
      fd1 += ff[o1*17+f]*dv;
      fd2 += ff[o2*17+f]*dv;
    }
    float v = (aa*fu1+(1.f-aa)*fd1)*Wout[o1];
    if (o2v) v += (aa*fu2+(1.f-aa)*fd2)*Wout[o2];
    #pragma unroll
    for (int off=32;off>=1;off>>=1) v += __shfl_xor(v,off,64);
    if (lane==0) outp[t*512+bg] = v + biasout[0];
  }
}

__global__ void kernC(const float* __restrict__ labels, float* __restrict__ outp){
  int p = blockIdx.x*256 + threadIdx.x;
  if (p < 16384){
    int t=p>>9, b=p&511;
    outp[16384+p] = labels[b*32+t];
  }
}

// ================= weight prep =================
__global__ void kprep(const float* __restrict__ Wih, const float* __restrict__ b_ih,
                      const float* __restrict__ b_hh, const float* __restrict__ Wt,
                      const float* __restrict__ bt_ih, const float* __restrict__ bt_hh,
                      const float* __restrict__ wp, const float* __restrict__ F1,
                      float* __restrict__ wsf)
{
  int n = blockIdx.x*256 + threadIdx.x;
  if (n < 184832){  // wp A-frags, 2 parities: k-cols map via ping-pong halves
    int p=n/92416, r=n%92416;
    int jp=r&3, lane=(r>>2)&63, rest=r>>8;
    int ks=rest%19, mt=rest/19;
    int m = mt*16 + (lane&15);
    int kb = ks*32 + (lane>>4)*8 + 2*jp;
    int c0 = 304*p, c1 = 304-c0;
    float v[2];
    #pragma unroll
    for (int q=0;q<2;q++){
      int kc = kb+q;
      float x = 0.f;
      if (m<300){
        if (kc>=c0 && kc<c0+300)      x = wp[m*600 + (kc-c0)];        // con_t  weights
        else if (kc>=c1 && kc<c1+300) x = wp[m*600 + 300 + (kc-c1)];  // con_t-1 weights
      }
      v[q]=x;
    }
    ((unsigned*)wsf)[OFF_WPA+n] = ((unsigned)f2usr(v[1])<<16) | f2usr(v[0]);
    return;
  }
  n -= 184832;
  if (n < 33280){   // F1 con-part B-frags: rel-k<300 -> F1[relk][col], else 0
    int jp=n&3, lane=(n>>2)&63, rest=n>>8;
    int ks=rest%10, nt=rest/10;
    int col = nt*16 + (lane&15);
    int rk = ks*32 + (lane>>4)*8 + 2*jp;
    float v0 = (col<200 && rk  <300)? F1[rk*200+col]     : 0.f;
    float v1 = (col<200 && rk+1<300)? F1[(rk+1)*200+col] : 0.f;
    ((unsigned*)wsf)[OFF_F1C+n] = ((unsigned)f2usr(v1)<<16) | f2usr(v0);
    return;
  }
  n -= 33280;
  if (n < 33280){   // F1 ht-part B-frags: rows 300..599
    int jp=n&3, lane=(n>>2)&63, rest=n>>8;
    int ks=rest%10, nt=rest/10;
    int col = nt*16 + (lane&15);
    int rk = ks*32 + (lane>>4)*8 + 2*jp;
    float v0 = (col<200 && rk  <300)? F1[(300+rk)*200+col]   : 0.f;
    float v1 = (col<200 && rk+1<300)? F1[(301+rk)*200+col]   : 0.f;
    ((unsigned*)wsf)[OFF_F1H+n] = ((unsigned)f2usr(v1)<<16) | f2usr(v0);
    return;
  }
  n -= 33280;
  if (n < 99000){
    int h=n%300; int q=n/300; int g=q%3; int m=q/3; int i=m%11; int k=m/11;
    int G = h + (g==0?0:(g==1?600:900));
    wsf[OFF_WIHP+n] = Wih[(k*1200 + G)*11 + i]; return;
  }
  n -= 99000;
  if (n < 9000){
    int h=n%300; int q=n/300; int g=q%3, k=q/3;
    int G = h + (g==0?0:(g==1?600:900));
    wsf[OFF_BCP+n] = b_ih[k*1200+G] + b_hh[k*1200+G]; return;
  }
  n -= 9000;
  if (n < 900){
    int h=n%300, g=n/300;
    int G = h + (g==0?0:(g==1?600:900));
    wsf[OFF_BTP+n] = bt_ih[G]+bt_hh[G]; return;
  }
  n -= 900;
  if (n < 3600){
    int h=n%300; int q=n/300; int g=q%3, e=q/3;
    int G = h + (g==0?0:(g==1?600:900));
    wsf[OFF_WTP+n] = Wt[G*4+e]; return;
  }
}

__global__ void kprep2(const float* __restrict__ DisM, float* __restrict__ wsf){
  if (threadIdx.x==0 && blockIdx.x==0){
    float m = DisM[0];
    for (int k=1;k<10;k++) m = fmaxf(m, DisM[k]);
    float e[10]; float s=0.f;
    for (int k=0;k<10;k++){ e[k]=__expf(DisM[k]-m); s+=e[k]; }
    float inv=1.0f/s; float sw=0.f;
    for (int k=0;k<10;k++){ float v=e[k]*inv; wsf[OFF_WA+k]=v; sw+=v; }
    wsf[OFF_SWA]=sw;
  }
}

extern "C" void kernel_launch(void* const* d_in, const int* in_sizes, int n_in,
                              void* d_out, int out_size, void* d_ws, size_t ws_size,
                              hipStream_t stream)
{
  const float* li     = (const float*)d_in[0];
  const float* labels = (const float*)d_in[1];
  const float* exs    = (const float*)d_in[2];
  const float* DisM   = (const float*)d_in[3];
  const float* AngleM = (const float*)d_in[4];
  const float* Wih    = (const float*)d_in[5];
  const float* b_ih   = (const float*)d_in[6];
  const float* b_hh   = (const float*)d_in[7];
  const float* Wt     = (const float*)d_in[8];
  const float* bt_ih  = (const float*)d_in[9];
  const float* bt_hh  = (const float*)d_in[10];
  const float* wp     = (const float*)d_in[11];
  const float* bp     = (const float*)d_in[12];
  const float* F1     = (const float*)d_in[13];
  const float* b1     = (const float*)d_in[14];
  const float* F2     = (const float*)d_in[15];
  const float* b2     = (const float*)d_in[16];
  const float* ff     = (const float*)d_in[17];
  const float* bff    = (const float*)d_in[18];
  const float* fuse1  = (const float*)d_in[19];
  const float* biasf  = (const float*)d_in[20];
  const float* Wout   = (const float*)d_in[21];
  const float* biasout= (const float*)d_in[22];
  const float* a      = (const float*)d_in[23];
  float* wsf = (float*)d_ws;
  float* outp = (float*)d_out;
  unsigned* con1u = (unsigned*)((char*)d_ws + CON1_BYTE);

  if (ws_size < WS_MIN_BYTES) return;  // proven available (R4 PATH1 ran)

  kprep<<<dim3(1422), dim3(256), 0, stream>>>(Wih,b_ih,b_hh,Wt,bt_ih,bt_hh,wp,F1,wsf);
  kprep2<<<dim3(1), dim3(64), 0, stream>>>(DisM, wsf);
  kern_main <<<dim3(128,4), NTHR, 0, stream>>>(li, exs, AngleM, bp, F2, b2, b1,
                                               wsf, con1u, wsf + OFF_SM);
  kern_final<<<dim3(128,32), NTHR, 0, stream>>>(li, ff, bff, fuse1, biasf, Wout, biasout, a,
                                                wsf, con1u, outp);
  kernC<<<dim3(64), dim3(256), 0, stream>>>(labels, outp);
}

// Round 10
// 807.579 us; speedup vs baseline: 1.3059x; 1.3059x over previous
//
#include <hip/hip_runtime.h>
#include <hip/hip_bf16.h>

// GCLSTM: B=512, T=32, H=300, K=10. f32 in/out.
// R10 = R7 (best: 828us) + WIHP2 repack: cells weights+biases as [k][h][36]
// (144B/point, 9x dwordx4, biases slots 33-35) replacing 36 strided scalar
// loads + addr chains per point. kernC fused into kern_final. NOTHING else
// changed (R8 MFMA-cells and R9 t-loop both regressed — structure stays R7).

#define TB 4
#define NTHR 640          // 10 waves
#define NW 10
#define KP 616

// ws layout (u32 slots)
#define OFF_SM    0         // softmax [32][10][512] f32          163840
#define OFF_WBF2  163840    // wp A-frags [mt19][ks19][lane64][4]  92416
#define OFF_F1S   256256    // F1 B-frags [nt13][ks19][lane64][4]  63232
#define OFF_WIHP2 319488    // cells [k10][h300][36] f32 (33-35=bias) 108000
#define OFF_BTP   427488    // g*300+h f32                           900
#define OFF_WTP   428388    // (e*3+g)*300+h f32                    3600
#define OFF_WA    431988    // softmax(DisM) f32                      10
#define OFF_SWA   431998    // sum(wA) f32                             1
#define BASE_U32  432000
#define CON1_BYTE ((size_t)BASE_U32 * 4)                  // 1,728,000
#define WS_MIN_BYTES (CON1_BYTE + (size_t)98304000)       // 100,032,000 (< proven 100,436,608)

typedef __attribute__((ext_vector_type(8))) short s16x8;
typedef __attribute__((ext_vector_type(4))) float f32x4;
typedef unsigned short u16;

__device__ __forceinline__ float sigf(float x){ return 1.0f/(1.0f+__expf(-x)); }
__device__ __forceinline__ float tanhf_(float x){ return 1.0f - 2.0f/(__expf(2.0f*x)+1.0f); }
__device__ __forceinline__ float bfu(u16 u){ return __uint_as_float(((unsigned)u)<<16); }
__device__ __forceinline__ u16 f2us(float f){ return (u16)(__float_as_uint(f)>>16); }
__device__ __forceinline__ u16 f2usr(float f){   // RNE bf16
  __hip_bfloat16 h = __float2bfloat16(f);
  return *(u16*)&h;
}

// ================= fused per-(t, b-tile) kernel, 10 waves =================
__global__ __launch_bounds__(NTHR,2) void kern_main(
    const float* __restrict__ li, const float* __restrict__ exs,
    const float* __restrict__ AngleM, const float* __restrict__ bp,
    const float* __restrict__ F2, const float* __restrict__ b2,
    const float* wsf, unsigned* __restrict__ con1u, float* smg)
{
  __shared__ __align__(16) u16 cct[48][KP];   // 59,136 B
  __shared__ float xs[2][TB][11][10];         //  3,520
  __shared__ float xse[TB][2][10];            //    320
  __shared__ float exss[TB][4];               //     64
  __shared__ float wdP[NW][48];               //  1,920
  __shared__ float wdL[48];                   //    192  (total 65,152 <= 65,536)
  const int tid = threadIdx.x;
  const int t = blockIdx.y, bt = blockIdx.x, b0 = bt*TB;
  const int w = tid>>6, lane = tid&63, lo = lane&15, qd = lane>>4;

  // ---- P0: stage inputs; zero cells K-pad cols [600,616) rows 0..39 ----
  for (int p=tid; p<2*TB*110; p+=NTHR){
    int half=p/440, r=p%440, b=r/110, q=r%110, i=q/10, k=q%10;
    int tp = half ? (t>0? t-1 : 0) : t;
    xs[half][b][i][k] = li[(((b0+b)*32+tp)*28+i)*10+k];
  }
  for (int p=tid;p<TB*20;p+=NTHR){
    int b=p/20, r=p%20, rr=r/10, k=r%10;
    xse[b][rr][k] = li[(((b0+b)*32+t)*28 + (rr?10:8))*10 + k];
  }
  for (int p=tid;p<TB*4;p+=NTHR){
    int b=p/4, e=p%4;
    exss[b][e] = exs[((b0+b)*32+t)*4+e];
  }
  for (int p=tid; p<40*4; p+=NTHR){
    int n=p/4, c=p%4;
    ((unsigned*)&cct[n][600])[c] = 0u;
  }
  __syncthreads();

  // ---- P1: cells for t (half 0) and t-1 (half 1); 9x dwordx4 per point ----
  const int nh = (t==0)?1:2;
  for (int pt=tid; pt<3000; pt+=NTHR){
    int k=pt/300, h=pt%300;
    const float4* Wp = (const float4*)(wsf + OFF_WIHP2 + (size_t)(k*300+h)*36);
    float f[36];
    #pragma unroll
    for (int q=0;q<9;q++){
      float4 v = Wp[q];
      f[4*q+0]=v.x; f[4*q+1]=v.y; f[4*q+2]=v.z; f[4*q+3]=v.w;
    }
    for (int half=0; half<nh; half++){
      #pragma unroll
      for (int b=0;b<TB;b++){
        float ai=f[33], ag=f[34], ao=f[35];
        #pragma unroll
        for (int i=0;i<11;i++){
          float xv = xs[half][b][i][k];
          ai += f[3*i+0]*xv; ag += f[3*i+1]*xv; ao += f[3*i+2]*xv;
        }
        float hv = sigf(ao) * tanhf_( sigf(ai) * tanhf_(ag) );
        cct[b*10+k][h+300*half] = f2usr(hv);
      }
    }
  }
  __syncthreads();

  // ---- P2: wp-MFMA  D[o 304][n 48] = W[304x608] @ cct[608x48]; 2 Mtiles/wave ----
  f32x4 acc[2][3];
  #pragma unroll
  for (int i=0;i<2;i++)
    #pragma unroll
    for (int nt=0;nt<3;nt++) acc[i][nt] = (f32x4){0.f,0.f,0.f,0.f};
  if (t>0){
    const u16* wbfA = (const u16*)((const unsigned*)wsf + OFF_WBF2);
    for (int ks=0; ks<19; ks++){
      const int kb = ks*32 + qd*8;
      s16x8 Bv[3];
      #pragma unroll
      for (int nt=0;nt<3;nt++)
        Bv[nt] = *(const s16x8*)&cct[nt*16+lo][kb];
      #pragma unroll
      for (int i=0;i<2;i++){
        int mt = w*2+i;
        if (mt<19){
          s16x8 Av = *(const s16x8*)(wbfA + ((size_t)(mt*19+ks)*64 + lane)*8);
          #pragma unroll
          for (int nt=0;nt<3;nt++)
            acc[i][nt] = __builtin_amdgcn_mfma_f32_16x16x32_bf16(Av, Bv[nt], acc[i][nt], 0,0,0);
        }
      }
    }
  }
  __syncthreads();   // all B-reads of cct done before hcat overwrite

  // ---- P2b (t>0): epilogue transpose: cct[n][o] = relu(D+bp) bf16, o<300 ----
  if (t>0){
    #pragma unroll
    for (int i=0;i<2;i++){
      int mt = w*2+i;
      if (mt<19 && (mt<18 || qd<3)){   // skip o in [300,304)
        int ob = mt*16 + qd*4;
        float p0=bp[ob], p1=bp[ob+1], p2=bp[ob+2], p3=bp[ob+3];
        #pragma unroll
        for (int nt=0;nt<3;nt++){
          int n = nt*16+lo;
          float v0=acc[i][nt][0]+p0, v1=acc[i][nt][1]+p1,
                v2=acc[i][nt][2]+p2, v3=acc[i][nt][3]+p3;
          unsigned w0 = ((unsigned)f2us(v1>0.f?v1:0.f)<<16) | f2us(v0>0.f?v0:0.f);
          unsigned w1 = ((unsigned)f2us(v3>0.f?v3:0.f)<<16) | f2us(v2>0.f?v2:0.f);
          *(unsigned*)&cct[n][ob]   = w0;
          *(unsigned*)&cct[n][ob+2] = w1;
        }
      }
    }
  }
  // ---- P3: htarget -> hcat cols [300,600); col 600 = 1.0 ----
  for (int p=tid; p<TB*300; p+=NTHR){
    int b=p/300, o=p%300;
    float ai=0.f, ag=0.f, ao=0.f;
    #pragma unroll
    for (int e=0;e<4;e++){
      float xv = exss[b][e];
      ai += wsf[OFF_WTP+(e*3+0)*300+o]*xv;
      ag += wsf[OFF_WTP+(e*3+1)*300+o]*xv;
      ao += wsf[OFF_WTP+(e*3+2)*300+o]*xv;
    }
    ai += wsf[OFF_BTP+o]; ag += wsf[OFF_BTP+300+o]; ao += wsf[OFF_BTP+600+o];
    u16 u = f2usr( sigf(ao)*tanhf_(sigf(ai)*tanhf_(ag)) );
    #pragma unroll
    for (int k=0;k<10;k++) cct[b*10+k][300+o] = u;
  }
  for (int p=tid; p<48*4; p+=NTHR){
    int n=p/4, c=p%4;
    ((unsigned*)&cct[n][600])[c] = (c==0)? 0x00003f80u : 0u;
  }
  __syncthreads();

  // ---- P5: store con1 tile [n 40][o 300] coalesced ----
  for (int p=tid; p<6000; p+=NTHR){
    int n=p/150, op=p%150;
    con1u[ ((size_t)(t*128+bt)*40 + n)*150 + op ] = *(const unsigned*)&cct[n][2*op];
  }

  // ---- P4: F1-MFMA  fc1[n 48][j 208] = hcat[48x608] @ F1[608x208]; nt in {w, w+10} ----
  f32x4 acc2[3][2];
  #pragma unroll
  for (int mt=0;mt<3;mt++)
    #pragma unroll
    for (int j=0;j<2;j++) acc2[mt][j] = (f32x4){0.f,0.f,0.f,0.f};
  {
    const u16* f1s = (const u16*)((const unsigned*)wsf + OFF_F1S);
    for (int ks=0; ks<19; ks++){
      const int kb = ks*32 + qd*8;
      s16x8 Am[3];
      #pragma unroll
      for (int mt=0;mt<3;mt++)
        Am[mt] = *(const s16x8*)&cct[mt*16+lo][kb];
      #pragma unroll
      for (int j=0;j<2;j++){
        int nt = w + j*NW;
        if (nt<13){
          s16x8 Bf = *(const s16x8*)(f1s + ((size_t)(nt*19+ks)*64 + lane)*8);
          #pragma unroll
          for (int mt=0;mt<3;mt++)
            acc2[mt][j] = __builtin_amdgcn_mfma_f32_16x16x32_bf16(Am[mt], Bf, acc2[mt][j], 0,0,0);
        }
      }
    }
  }
  // wdyn partials: relu(fc1)*F2, sum this wave's j-cols, reduce within quads
  {
    float f2c[2];
    #pragma unroll
    for (int j=0;j<2;j++){
      int nt = w + j*NW;
      int jj = nt*16+lo;
      f2c[j] = (nt<13 && jj<200)? F2[jj] : 0.f;
    }
    #pragma unroll
    for (int mt=0;mt<3;mt++)
      #pragma unroll
      for (int r=0;r<4;r++){
        float s = 0.f;
        #pragma unroll
        for (int j=0;j<2;j++){
          float v = acc2[mt][j][r];
          s += (v>0.f? v:0.f) * f2c[j];
        }
        s += __shfl_xor(s,1,64); s += __shfl_xor(s,2,64);
        s += __shfl_xor(s,4,64); s += __shfl_xor(s,8,64);
        if (lo==0) wdP[w][mt*16+qd*4+r] = s;
      }
  }
  __syncthreads();
  if (tid<40){
    int n=tid, b=n/10, k=n%10;
    float v = 0.f;
    #pragma unroll
    for (int ww=0;ww<NW;ww++) v += wdP[ww][n];
    float ang = fabsf(xse[b][1][k]-AngleM[k]) * (1.0f/360.0f);
    v += xse[b][0][k]*F2[200] + ang*F2[201] + b2[0];
    wdL[n] = v>0.f? v : 0.f;
  }
  __syncthreads();
  if (tid<TB){
    int b=tid;
    float m = wdL[b*10];
    #pragma unroll
    for (int k=1;k<10;k++) m = fmaxf(m, wdL[b*10+k]);
    float e[10]; float s=0.f;
    #pragma unroll
    for (int k=0;k<10;k++){ e[k]=__expf(wdL[b*10+k]-m); s+=e[k]; }
    float inv = 1.0f/s;
    #pragma unroll
    for (int k=0;k<10;k++) smg[t*5120 + k*512 + b0+b] = e[k]*inv;
  }
}

// ====== final: gather scramble, fuse, preds (+ labels copy fused) ======
__global__ __launch_bounds__(NTHR,3) void kern_final(
    const float* __restrict__ li, const float* __restrict__ labels,
    const float* __restrict__ ff, const float* __restrict__ bff,
    const float* __restrict__ fuse1, const float* __restrict__ biasf,
    const float* __restrict__ Wout, const float* __restrict__ biasout,
    const float* __restrict__ a, const float* wsf,
    const unsigned* __restrict__ con1u, float* __restrict__ outp)
{
  __shared__ unsigned conTu[40][152];   // [n][o-pairs]; u16 view stride 304
  __shared__ float xs17[TB][17][10];
  __shared__ float cats[TB][300];
  __shared__ float wa3s[TB][10];
  __shared__ float dss[TB][17];
  __shared__ float wAs[10];
  __shared__ float fup1[8][64], fup2[8][64];
  const int tid=threadIdx.x, t=blockIdx.y, bt=blockIdx.x, b0=bt*TB;
  if (tid>=NTHR-TB && tid<NTHR){   // fused kernC: labels_r for this (t, b-tile)
    int b = tid-(NTHR-TB);
    outp[16384 + t*512 + b0+b] = labels[(b0+b)*32+t];
  }
  for (int p=tid;p<TB*170;p+=NTHR){
    int b=p/170, r=p%170, f=r/10, k=r%10;
    xs17[b][f][k] = li[(((b0+b)*32+t)*28 + 11+f)*10 + k];
  }
  if (tid<10) wAs[tid] = wsf[OFF_WA+tid];
  for (int p=tid;p<6000;p+=NTHR){
    int n=p/150, op=p%150;
    conTu[n][op] = con1u[ ((size_t)(t*128+bt)*40 + n)*150 + op ];
  }
  __syncthreads();
  for (int p=tid;p<TB*10;p+=NTHR){
    int b=p/10, k=p%10;
    int g = (b0+b)*10+k;   // flat-reshape scramble of the [10,512] softmax matrix
    wa3s[b][k] = wsf[OFF_SM + t*5120 + (g>>9)*512 + (g&511)];
  }
  for (int p=tid;p<TB*17;p+=NTHR){
    int b=p/17, f=p%17; float s=0.f;
    #pragma unroll
    for (int k=0;k<10;k++) s += xs17[b][f][k]*wAs[k];
    dss[b][f]=s;
  }
  __syncthreads();
  const u16* conT = (const u16*)conTu;
  for (int p=tid;p<TB*300;p+=NTHR){
    int b=p/300, h=p%300;
    float s=0.f;
    #pragma unroll
    for (int k=0;k<10;k++)
      s += bfu(conT[(b*10+k)*304 + h]) * wa3s[b][k];
    cats[b][h]=s;
  }
  __syncthreads();
  const int w = tid>>6, lane = tid&63;
  const int o1 = lane;
  const bool o2v = lane<36;
  const int o2 = o2v ? (64+lane) : 99;
  if (w<8){   // fuse1 partials: wave = (b, half of h-range)
    int b=w>>1, half=w&1;
    float fu1 = half? 0.f : biasf[o1];
    float fu2 = half? 0.f : biasf[o2];
    const int hb = half*150;
    for (int h=hb; h<hb+150; h++){
      float cv = cats[b][h];
      fu1 += cv*fuse1[h*100+o1];
      fu2 += cv*fuse1[h*100+o2];
    }
    fup1[w][lane]=fu1; fup2[w][lane]=fu2;
  }
  __syncthreads();
  if (w<TB){
    const int b=w, bg=b0+b;
    const float aa = a[0], swa = wsf[OFF_SWA];
    float fu1 = fup1[2*b][lane] + fup1[2*b+1][lane];
    float fu2 = fup2[2*b][lane] + fup2[2*b+1][lane];
    float fd1 = bff[o1]*swa, fd2 = bff[o2]*swa;
    #pragma unroll
    for (int f=0;f<17;f++){
      float dv = dss[b][f];
      fd1 += ff[o1*17+f]*dv;
      fd2 += ff[o2*17+f]*dv;
    }
    float v = (aa*fu1+(1.f-aa)*fd1)*Wout[o1];
    if (o2v) v += (aa*fu2+(1.f-aa)*fd2)*Wout[o2];
    #pragma unroll
    for (int off=32;off>=1;off>>=1) v += __shfl_xor(v,off,64);
    if (lane==0) outp[t*512+bg] = v + biasout[0];
  }
}

// ================= weight prep =================
__global__ void kprep(const float* __restrict__ Wih, const float* __restrict__ b_ih,
                      const float* __restrict__ b_hh, const float* __restrict__ Wt,
                      const float* __restrict__ bt_ih, const float* __restrict__ bt_hh,
                      const float* __restrict__ wp, const float* __restrict__ F1,
                      const float* __restrict__ b1, float* __restrict__ wsf)
{
  int n = blockIdx.x*256 + threadIdx.x;
  if (n < 92416){   // wp A-frags: [mt][ks][lane][4 u32]
    int jp=n&3, lane=(n>>2)&63, rest=n>>8;
    int ks=rest%19, mt=rest/19;
    int m = mt*16 + (lane&15);
    int k = ks*32 + (lane>>4)*8 + 2*jp;
    float v0 = (m<300 && k  <600)? wp[m*600+k  ] : 0.f;
    float v1 = (m<300 && k+1<600)? wp[m*600+k+1] : 0.f;
    ((unsigned*)wsf)[OFF_WBF2+n] = ((unsigned)f2usr(v1)<<16) | f2usr(v0);
    return;
  }
  n -= 92416;
  if (n < 63232){   // F1 B-frags: [nt][ks][lane][4]; row 600 = b1
    int jp=n&3, lane=(n>>2)&63, rest=n>>8;
    int ks=rest%19, nt=rest/19;
    int col = nt*16 + (lane&15);
    int k = ks*32 + (lane>>4)*8 + 2*jp;
    float v0=0.f, v1=0.f;
    if (col<200){
      v0 = (k  <600)? F1[k*200+col]     : (k  ==600? b1[col] : 0.f);
      v1 = (k+1<600)? F1[(k+1)*200+col] : (k+1==600? b1[col] : 0.f);
    }
    ((unsigned*)wsf)[OFF_F1S+n] = ((unsigned)f2usr(v1)<<16) | f2usr(v0);
    return;
  }
  n -= 63232;
  if (n < 108000){  // cells WIHP2 [k][h][36]: slot 3i+g = Wih_g[i]; 33..35 = biases
    int k=n/10800, r=n%10800, h=r/36, s=r%36;
    float v;
    if (s<33){
      int i=s/3, g=s%3;
      int G = h + (g==0?0:(g==1?600:900));
      v = Wih[(k*1200+G)*11 + i];
    } else {
      int g=s-33;
      int G = h + (g==0?0:(g==1?600:900));
      v = b_ih[k*1200+G] + b_hh[k*1200+G];
    }
    wsf[OFF_WIHP2+n] = v; return;
  }
  n -= 108000;
  if (n < 900){
    int h=n%300, g=n/300;
    int G = h + (g==0?0:(g==1?600:900));
    wsf[OFF_BTP+n] = bt_ih[G]+bt_hh[G]; return;
  }
  n -= 900;
  if (n < 3600){
    int h=n%300; int q=n/300; int g=q%3, e=q/3;
    int G = h + (g==0?0:(g==1?600:900));
    wsf[OFF_WTP+n] = Wt[G*4+e]; return;
  }
}

__global__ void kprep2(const float* __restrict__ DisM, float* __restrict__ wsf){
  if (threadIdx.x==0 && blockIdx.x==0){
    float m = DisM[0];
    for (int k=1;k<10;k++) m = fmaxf(m, DisM[k]);
    float e[10]; float s=0.f;
    for (int k=0;k<10;k++){ e[k]=__expf(DisM[k]-m); s+=e[k]; }
    float inv=1.0f/s; float sw=0.f;
    for (int k=0;k<10;k++){ float v=e[k]*inv; wsf[OFF_WA+k]=v; sw+=v; }
    wsf[OFF_SWA]=sw;
  }
}

extern "C" void kernel_launch(void* const* d_in, const int* in_sizes, int n_in,
                              void* d_out, int out_size, void* d_ws, size_t ws_size,
                              hipStream_t stream)
{
  const float* li     = (const float*)d_in[0];
  const float* labels = (const float*)d_in[1];
  const float* exs    = (const float*)d_in[2];
  const float* DisM   = (const float*)d_in[3];
  const float* AngleM = (const float*)d_in[4];
  const float* Wih    = (const float*)d_in[5];
  const float* b_ih   = (const float*)d_in[6];
  const float* b_hh   = (const float*)d_in[7];
  const float* Wt     = (const float*)d_in[8];
  const float* bt_ih  = (const float*)d_in[9];
  const float* bt_hh  = (const float*)d_in[10];
  const float* wp     = (const float*)d_in[11];
  const float* bp     = (const float*)d_in[12];
  const float* F1     = (const float*)d_in[13];
  const float* b1     = (const float*)d_in[14];
  const float* F2     = (const float*)d_in[15];
  const float* b2     = (const float*)d_in[16];
  const float* ff     = (const float*)d_in[17];
  const float* bff    = (const float*)d_in[18];
  const float* fuse1  = (const float*)d_in[19];
  const float* biasf  = (const float*)d_in[20];
  const float* Wout   = (const float*)d_in[21];
  const float* biasout= (const float*)d_in[22];
  const float* a      = (const float*)d_in[23];
  float* wsf = (float*)d_ws;
  float* outp = (float*)d_out;
  unsigned* con1u = (unsigned*)((char*)d_ws + CON1_BYTE);

  if (ws_size < WS_MIN_BYTES) return;  // proven available (R4 PATH1 ran)

  kprep<<<dim3(1048), dim3(256), 0, stream>>>(Wih,b_ih,b_hh,Wt,bt_ih,bt_hh,wp,F1,b1,wsf);
  kprep2<<<dim3(1), dim3(64), 0, stream>>>(DisM, wsf);
  kern_main <<<dim3(128,32), NTHR, 0, stream>>>(li, exs, AngleM, bp, F2, b2,
                                                wsf, con1u, wsf + OFF_SM);
  kern_final<<<dim3(128,32), NTHR, 0, stream>>>(li, labels, ff, bff, fuse1, biasf,
                                                Wout, biasout, a, wsf, con1u, outp);
}

// Round 11
// 752.814 us; speedup vs baseline: 1.4009x; 1.0727x over previous
//
#include <hip/hip_runtime.h>
#include <hip/hip_bf16.h>

// GCLSTM: B=512, T=32, H=300, K=10. f32 in/out.
// R11 = R10 with TB 4->2 (one variable): cct[32][616] ~42.8KB LDS -> 3
// blocks/CU co-resident (was 2, measured ~1 effective). Barrier/latency skew
// overlaps across 50% more waves. GEMM N=32 (rows 20-31 zero, junk discarded
// by n<20 guards). kern_final stays TBF=4, gathers con1u from 2-wide tiles.

#define TB 2
#define NR 32             // cct rows (MFMA N)
#define NTHR 640          // 10 waves
#define NW 10
#define KP 616
#define TBF 4             // kern_final b-tile

// ws layout (u32 slots) — identical to R10
#define OFF_SM    0         // softmax [32][10][512] f32          163840
#define OFF_WBF2  163840    // wp A-frags [mt19][ks19][lane64][4]  92416
#define OFF_F1S   256256    // F1 B-frags [nt13][ks19][lane64][4]  63232
#define OFF_WIHP2 319488    // cells [k10][h300][36] f32 (33-35=bias) 108000
#define OFF_BTP   427488    // g*300+h f32                           900
#define OFF_WTP   428388    // (e*3+g)*300+h f32                    3600
#define OFF_WA    431988    // softmax(DisM) f32                      10
#define OFF_SWA   431998    // sum(wA) f32                             1
#define BASE_U32  432000
#define CON1_BYTE ((size_t)BASE_U32 * 4)                  // 1,728,000
#define WS_MIN_BYTES (CON1_BYTE + (size_t)98304000)       // 100,032,000 (< proven 100,436,608)

typedef __attribute__((ext_vector_type(8))) short s16x8;
typedef __attribute__((ext_vector_type(4))) float f32x4;
typedef unsigned short u16;

__device__ __forceinline__ float sigf(float x){ return 1.0f/(1.0f+__expf(-x)); }
__device__ __forceinline__ float tanhf_(float x){ return 1.0f - 2.0f/(__expf(2.0f*x)+1.0f); }
__device__ __forceinline__ float bfu(u16 u){ return __uint_as_float(((unsigned)u)<<16); }
__device__ __forceinline__ u16 f2us(float f){ return (u16)(__float_as_uint(f)>>16); }
__device__ __forceinline__ u16 f2usr(float f){   // RNE bf16
  __hip_bfloat16 h = __float2bfloat16(f);
  return *(u16*)&h;
}

// ================= fused per-(t, b-tile2) kernel, 10 waves =================
__global__ __launch_bounds__(NTHR,2) void kern_main(
    const float* __restrict__ li, const float* __restrict__ exs,
    const float* __restrict__ AngleM, const float* __restrict__ bp,
    const float* __restrict__ F2, const float* __restrict__ b2,
    const float* wsf, unsigned* __restrict__ con1u, float* smg)
{
  __shared__ __align__(16) u16 cct[NR][KP];   // 39,424 B
  __shared__ float xs[2][TB][11][10];         //  1,760
  __shared__ float xse[TB][2][10];            //    160
  __shared__ float exss[TB][4];               //     32
  __shared__ float wdP[NW][NR];               //  1,280
  __shared__ float wdL[NR];                   //    128  (total ~42.8 KB)
  const int tid = threadIdx.x;
  const int t = blockIdx.y, bt = blockIdx.x, b0 = bt*TB;
  const int w = tid>>6, lane = tid&63, lo = lane&15, qd = lane>>4;

  // ---- P0: stage inputs; zero K-pad (rows 0..19 cols 600-607) + rows 20..31 ----
  for (int p=tid; p<2*TB*110; p+=NTHR){
    int half=p/(110*TB), r=p%(110*TB), b=r/110, q=r%110, i=q/10, k=q%10;
    int tp = half ? (t>0? t-1 : 0) : t;
    xs[half][b][i][k] = li[(((b0+b)*32+tp)*28+i)*10+k];
  }
  for (int p=tid;p<TB*20;p+=NTHR){
    int b=p/20, r=p%20, rr=r/10, k=r%10;
    xse[b][rr][k] = li[(((b0+b)*32+t)*28 + (rr?10:8))*10 + k];
  }
  for (int p=tid;p<TB*4;p+=NTHR){
    int b=p/4, e=p%4;
    exss[b][e] = exs[((b0+b)*32+t)*4+e];
  }
  for (int p=tid; p<20*4; p+=NTHR){            // rows 0..19, cols 600-607
    int n=p/4, c=p%4;
    ((unsigned*)&cct[n][600])[c] = 0u;
  }
  for (int p=tid; p<12*(KP/2); p+=NTHR){       // rows 20..31 full
    int n=20+p/(KP/2), c=p%(KP/2);
    ((unsigned*)&cct[n][0])[c] = 0u;
  }
  __syncthreads();

  // ---- P1: cells for t (half 0) and t-1 (half 1); 9x dwordx4 per point ----
  const int nh = (t==0)?1:2;
  for (int pt=tid; pt<3000; pt+=NTHR){
    int k=pt/300, h=pt%300;
    const float4* Wp = (const float4*)(wsf + OFF_WIHP2 + (size_t)(k*300+h)*36);
    float f[36];
    #pragma unroll
    for (int q=0;q<9;q++){
      float4 v = Wp[q];
      f[4*q+0]=v.x; f[4*q+1]=v.y; f[4*q+2]=v.z; f[4*q+3]=v.w;
    }
    for (int half=0; half<nh; half++){
      #pragma unroll
      for (int b=0;b<TB;b++){
        float ai=f[33], ag=f[34], ao=f[35];
        #pragma unroll
        for (int i=0;i<11;i++){
          float xv = xs[half][b][i][k];
          ai += f[3*i+0]*xv; ag += f[3*i+1]*xv; ao += f[3*i+2]*xv;
        }
        float hv = sigf(ao) * tanhf_( sigf(ai) * tanhf_(ag) );
        cct[b*10+k][h+300*half] = f2usr(hv);
      }
    }
  }
  __syncthreads();

  // ---- P2: wp-MFMA  D[o 304][n 32]; 2 Mtiles/wave, 2 Ntiles ----
  f32x4 acc[2][2];
  #pragma unroll
  for (int i=0;i<2;i++)
    #pragma unroll
    for (int nt=0;nt<2;nt++) acc[i][nt] = (f32x4){0.f,0.f,0.f,0.f};
  if (t>0){
    const u16* wbfA = (const u16*)((const unsigned*)wsf + OFF_WBF2);
    for (int ks=0; ks<19; ks++){
      const int kb = ks*32 + qd*8;
      s16x8 Bv[2];
      #pragma unroll
      for (int nt=0;nt<2;nt++)
        Bv[nt] = *(const s16x8*)&cct[nt*16+lo][kb];
      #pragma unroll
      for (int i=0;i<2;i++){
        int mt = w*2+i;
        if (mt<19){
          s16x8 Av = *(const s16x8*)(wbfA + ((size_t)(mt*19+ks)*64 + lane)*8);
          #pragma unroll
          for (int nt=0;nt<2;nt++)
            acc[i][nt] = __builtin_amdgcn_mfma_f32_16x16x32_bf16(Av, Bv[nt], acc[i][nt], 0,0,0);
        }
      }
    }
  }
  __syncthreads();   // all B-reads of cct done before hcat overwrite

  // ---- P2b (t>0): epilogue transpose: cct[n][o] = relu(D+bp) bf16, o<300 ----
  if (t>0){
    #pragma unroll
    for (int i=0;i<2;i++){
      int mt = w*2+i;
      if (mt<19 && (mt<18 || qd<3)){   // skip o in [300,304)
        int ob = mt*16 + qd*4;
        float p0=bp[ob], p1=bp[ob+1], p2=bp[ob+2], p3=bp[ob+3];
        #pragma unroll
        for (int nt=0;nt<2;nt++){
          int n = nt*16+lo;
          float v0=acc[i][nt][0]+p0, v1=acc[i][nt][1]+p1,
                v2=acc[i][nt][2]+p2, v3=acc[i][nt][3]+p3;
          unsigned w0 = ((unsigned)f2us(v1>0.f?v1:0.f)<<16) | f2us(v0>0.f?v0:0.f);
          unsigned w1 = ((unsigned)f2us(v3>0.f?v3:0.f)<<16) | f2us(v2>0.f?v2:0.f);
          *(unsigned*)&cct[n][ob]   = w0;
          *(unsigned*)&cct[n][ob+2] = w1;
        }
      }
    }
  }
  // ---- P3: htarget -> hcat cols [300,600); col 600 = 1.0 (rows 0..19) ----
  for (int p=tid; p<TB*300; p+=NTHR){
    int b=p/300, o=p%300;
    float ai=0.f, ag=0.f, ao=0.f;
    #pragma unroll
    for (int e=0;e<4;e++){
      float xv = exss[b][e];
      ai += wsf[OFF_WTP+(e*3+0)*300+o]*xv;
      ag += wsf[OFF_WTP+(e*3+1)*300+o]*xv;
      ao += wsf[OFF_WTP+(e*3+2)*300+o]*xv;
    }
    ai += wsf[OFF_BTP+o]; ag += wsf[OFF_BTP+300+o]; ao += wsf[OFF_BTP+600+o];
    u16 u = f2usr( sigf(ao)*tanhf_(sigf(ai)*tanhf_(ag)) );
    #pragma unroll
    for (int k=0;k<10;k++) cct[b*10+k][300+o] = u;
  }
  for (int p=tid; p<20*4; p+=NTHR){
    int n=p/4, c=p%4;
    ((unsigned*)&cct[n][600])[c] = (c==0)? 0x00003f80u : 0u;
  }
  __syncthreads();

  // ---- P5: store con1 tile [n 20][o 300] coalesced ----
  for (int p=tid; p<TB*1500; p+=NTHR){
    int n=p/150, op=p%150;
    con1u[ ((size_t)(t*256+bt)*20 + n)*150 + op ] = *(const unsigned*)&cct[n][2*op];
  }

  // ---- P4: F1-MFMA  fc1[n 32][j 208]; 2 Mtiles, nt in {w, w+10} ----
  f32x4 acc2[2][2];
  #pragma unroll
  for (int mt=0;mt<2;mt++)
    #pragma unroll
    for (int j=0;j<2;j++) acc2[mt][j] = (f32x4){0.f,0.f,0.f,0.f};
  {
    const u16* f1s = (const u16*)((const unsigned*)wsf + OFF_F1S);
    for (int ks=0; ks<19; ks++){
      const int kb = ks*32 + qd*8;
      s16x8 Am[2];
      #pragma unroll
      for (int mt=0;mt<2;mt++)
        Am[mt] = *(const s16x8*)&cct[mt*16+lo][kb];
      #pragma unroll
      for (int j=0;j<2;j++){
        int nt = w + j*NW;
        if (nt<13){
          s16x8 Bf = *(const s16x8*)(f1s + ((size_t)(nt*19+ks)*64 + lane)*8);
          #pragma unroll
          for (int mt=0;mt<2;mt++)
            acc2[mt][j] = __builtin_amdgcn_mfma_f32_16x16x32_bf16(Am[mt], Bf, acc2[mt][j], 0,0,0);
        }
      }
    }
  }
  // wdyn partials: relu(fc1)*F2, sum this wave's j-cols, reduce within quads
  {
    float f2c[2];
    #pragma unroll
    for (int j=0;j<2;j++){
      int nt = w + j*NW;
      int jj = nt*16+lo;
      f2c[j] = (nt<13 && jj<200)? F2[jj] : 0.f;
    }
    #pragma unroll
    for (int mt=0;mt<2;mt++)
      #pragma unroll
      for (int r=0;r<4;r++){
        float s = 0.f;
        #pragma unroll
        for (int j=0;j<2;j++){
          float v = acc2[mt][j][r];
          s += (v>0.f? v:0.f) * f2c[j];
        }
        s += __shfl_xor(s,1,64); s += __shfl_xor(s,2,64);
        s += __shfl_xor(s,4,64); s += __shfl_xor(s,8,64);
        if (lo==0) wdP[w][mt*16+qd*4+r] = s;
      }
  }
  __syncthreads();
  if (tid<TB*10){
    int n=tid, b=n/10, k=n%10;
    float v = 0.f;
    #pragma unroll
    for (int ww=0;ww<NW;ww++) v += wdP[ww][n];
    float ang = fabsf(xse[b][1][k]-AngleM[k]) * (1.0f/360.0f);
    v += xse[b][0][k]*F2[200] + ang*F2[201] + b2[0];
    wdL[n] = v>0.f? v : 0.f;
  }
  __syncthreads();
  if (tid<TB){
    int b=tid;
    float m = wdL[b*10];
    #pragma unroll
    for (int k=1;k<10;k++) m = fmaxf(m, wdL[b*10+k]);
    float e[10]; float s=0.f;
    #pragma unroll
    for (int k=0;k<10;k++){ e[k]=__expf(wdL[b*10+k]-m); s+=e[k]; }
    float inv = 1.0f/s;
    #pragma unroll
    for (int k=0;k<10;k++) smg[t*5120 + k*512 + b0+b] = e[k]*inv;
  }
}

// ====== final: gather scramble, fuse, preds (+ labels copy fused); TBF=4 ======
__global__ __launch_bounds__(NTHR,3) void kern_final(
    const float* __restrict__ li, const float* __restrict__ labels,
    const float* __restrict__ ff, const float* __restrict__ bff,
    const float* __restrict__ fuse1, const float* __restrict__ biasf,
    const float* __restrict__ Wout, const float* __restrict__ biasout,
    const float* __restrict__ a, const float* wsf,
    const unsigned* __restrict__ con1u, float* __restrict__ outp)
{
  __shared__ unsigned conTu[40][152];   // [n][o-pairs]; u16 view stride 304
  __shared__ float xs17[TBF][17][10];
  __shared__ float cats[TBF][300];
  __shared__ float wa3s[TBF][10];
  __shared__ float dss[TBF][17];
  __shared__ float wAs[10];
  __shared__ float fup1[8][64], fup2[8][64];
  const int tid=threadIdx.x, t=blockIdx.y, bt=blockIdx.x, b0=bt*TBF;
  if (tid>=NTHR-TBF && tid<NTHR){   // fused kernC: labels_r for this (t, b-tile)
    int b = tid-(NTHR-TBF);
    outp[16384 + t*512 + b0+b] = labels[(b0+b)*32+t];
  }
  for (int p=tid;p<TBF*170;p+=NTHR){
    int b=p/170, r=p%170, f=r/10, k=r%10;
    xs17[b][f][k] = li[(((b0+b)*32+t)*28 + 11+f)*10 + k];
  }
  if (tid<10) wAs[tid] = wsf[OFF_WA+tid];
  for (int p=tid;p<6000;p+=NTHR){   // gather from 2-wide tiles of kern_main
    int n4=p/150, op=p%150;
    int b=n4/10, k=n4%10, bg=b0+b;
    conTu[n4][op] = con1u[ ((size_t)(t*256+(bg>>1))*20 + (bg&1)*10 + k)*150 + op ];
  }
  __syncthreads();
  for (int p=tid;p<TBF*10;p+=NTHR){
    int b=p/10, k=p%10;
    int g = (b0+b)*10+k;   // flat-reshape scramble of the [10,512] softmax matrix
    wa3s[b][k] = wsf[OFF_SM + t*5120 + (g>>9)*512 + (g&511)];
  }
  for (int p=tid;p<TBF*17;p+=NTHR){
    int b=p/17, f=p%17; float s=0.f;
    #pragma unroll
    for (int k=0;k<10;k++) s += xs17[b][f][k]*wAs[k];
    dss[b][f]=s;
  }
  __syncthreads();
  const u16* conT = (const u16*)conTu;
  for (int p=tid;p<TBF*300;p+=NTHR){
    int b=p/300, h=p%300;
    float s=0.f;
    #pragma unroll
    for (int k=0;k<10;k++)
      s += bfu(conT[(b*10+k)*304 + h]) * wa3s[b][k];
    cats[b][h]=s;
  }
  __syncthreads();
  const int w = tid>>6, lane = tid&63;
  const int o1 = lane;
  const bool o2v = lane<36;
  const int o2 = o2v ? (64+lane) : 99;
  if (w<8){   // fuse1 partials: wave = (b, half of h-range)
    int b=w>>1, half=w&1;
    float fu1 = half? 0.f : biasf[o1];
    float fu2 = half? 0.f : biasf[o2];
    const int hb = half*150;
    for (int h=hb; h<hb+150; h++){
      float cv = cats[b][h];
      fu1 += cv*fuse1[h*100+o1];
      fu2 += cv*fuse1[h*100+o2];
    }
    fup1[w][lane]=fu1; fup2[w][lane]=fu2;
  }
  __syncthreads();
  if (w<TBF){
    const int b=w, bg=b0+b;
    const float aa = a[0], swa = wsf[OFF_SWA];
    float fu1 = fup1[2*b][lane] + fup1[2*b+1][lane];
    float fu2 = fup2[2*b][lane] + fup2[2*b+1][lane];
    float fd1 = bff[o1]*swa, fd2 = bff[o2]*swa;
    #pragma unroll
    for (int f=0;f<17;f++){
      float dv = dss[b][f];
      fd1 += ff[o1*17+f]*dv;
      fd2 += ff[o2*17+f]*dv;
    }
    float v = (aa*fu1+(1.f-aa)*fd1)*Wout[o1];
    if (o2v) v += (aa*fu2+(1.f-aa)*fd2)*Wout[o2];
    #pragma unroll
    for (int off=32;off>=1;off>>=1) v += __shfl_xor(v,off,64);
    if (lane==0) outp[t*512+bg] = v + biasout[0];
  }
}

// ================= weight prep (identical to R10) =================
__global__ void kprep(const float* __restrict__ Wih, const float* __restrict__ b_ih,
                      const float* __restrict__ b_hh, const float* __restrict__ Wt,
                      const float* __restrict__ bt_ih, const float* __restrict__ bt_hh,
                      const float* __restrict__ wp, const float* __restrict__ F1,
                      const float* __restrict__ b1, float* __restrict__ wsf)
{
  int n = blockIdx.x*256 + threadIdx.x;
  if (n < 92416){   // wp A-frags: [mt][ks][lane][4 u32]
    int jp=n&3, lane=(n>>2)&63, rest=n>>8;
    int ks=rest%19, mt=rest/19;
    int m = mt*16 + (lane&15);
    int k = ks*32 + (lane>>4)*8 + 2*jp;
    float v0 = (m<300 && k  <600)? wp[m*600+k  ] : 0.f;
    float v1 = (m<300 && k+1<600)? wp[m*600+k+1] : 0.f;
    ((unsigned*)wsf)[OFF_WBF2+n] = ((unsigned)f2usr(v1)<<16) | f2usr(v0);
    return;
  }
  n -= 92416;
  if (n < 63232){   // F1 B-frags: [nt][ks][lane][4]; row 600 = b1
    int jp=n&3, lane=(n>>2)&63, rest=n>>8;
    int ks=rest%19, nt=rest/19;
    int col = nt*16 + (lane&15);
    int k = ks*32 + (lane>>4)*8 + 2*jp;
    float v0=0.f, v1=0.f;
    if (col<200){
      v0 = (k  <600)? F1[k*200+col]     : (k  ==600? b1[col] : 0.f);
      v1 = (k+1<600)? F1[(k+1)*200+col] : (k+1==600? b1[col] : 0.f);
    }
    ((unsigned*)wsf)[OFF_F1S+n] = ((unsigned)f2usr(v1)<<16) | f2usr(v0);
    return;
  }
  n -= 63232;
  if (n < 108000){  // cells WIHP2 [k][h][36]: slot 3i+g = Wih_g[i]; 33..35 = biases
    int k=n/10800, r=n%10800, h=r/36, s=r%36;
    float v;
    if (s<33){
      int i=s/3, g=s%3;
      int G = h + (g==0?0:(g==1?600:900));
      v = Wih[(k*1200+G)*11 + i];
    } else {
      int g=s-33;
      int G = h + (g==0?0:(g==1?600:900));
      v = b_ih[k*1200+G] + b_hh[k*1200+G];
    }
    wsf[OFF_WIHP2+n] = v; return;
  }
  n -= 108000;
  if (n < 900){
    int h=n%300, g=n/300;
    int G = h + (g==0?0:(g==1?600:900));
    wsf[OFF_BTP+n] = bt_ih[G]+bt_hh[G]; return;
  }
  n -= 900;
  if (n < 3600){
    int h=n%300; int q=n/300; int g=q%3, e=q/3;
    int G = h + (g==0?0:(g==1?600:900));
    wsf[OFF_WTP+n] = Wt[G*4+e]; return;
  }
}

__global__ void kprep2(const float* __restrict__ DisM, float* __restrict__ wsf){
  if (threadIdx.x==0 && blockIdx.x==0){
    float m = DisM[0];
    for (int k=1;k<10;k++) m = fmaxf(m, DisM[k]);
    float e[10]; float s=0.f;
    for (int k=0;k<10;k++){ e[k]=__expf(DisM[k]-m); s+=e[k]; }
    float inv=1.0f/s; float sw=0.f;
    for (int k=0;k<10;k++){ float v=e[k]*inv; wsf[OFF_WA+k]=v; sw+=v; }
    wsf[OFF_SWA]=sw;
  }
}

extern "C" void kernel_launch(void* const* d_in, const int* in_sizes, int n_in,
                              void* d_out, int out_size, void* d_ws, size_t ws_size,
                              hipStream_t stream)
{
  const float* li     = (const float*)d_in[0];
  const float* labels = (const float*)d_in[1];
  const float* exs    = (const float*)d_in[2];
  const float* DisM   = (const float*)d_in[3];
  const float* AngleM = (const float*)d_in[4];
  const float* Wih    = (const float*)d_in[5];
  const float* b_ih   = (const float*)d_in[6];
  const float* b_hh   = (const float*)d_in[7];
  const float* Wt     = (const float*)d_in[8];
  const float* bt_ih  = (const float*)d_in[9];
  const float* bt_hh  = (const float*)d_in[10];
  const float* wp     = (const float*)d_in[11];
  const float* bp     = (const float*)d_in[12];
  const float* F1     = (const float*)d_in[13];
  const float* b1     = (const float*)d_in[14];
  const float* F2     = (const float*)d_in[15];
  const float* b2     = (const float*)d_in[16];
  const float* ff     = (const float*)d_in[17];
  const float* bff    = (const float*)d_in[18];
  const float* fuse1  = (const float*)d_in[19];
  const float* biasf  = (const float*)d_in[20];
  const float* Wout   = (const float*)d_in[21];
  const float* biasout= (const float*)d_in[22];
  const float* a      = (const float*)d_in[23];
  float* wsf = (float*)d_ws;
  float* outp = (float*)d_out;
  unsigned* con1u = (unsigned*)((char*)d_ws + CON1_BYTE);

  if (ws_size < WS_MIN_BYTES) return;  // proven available (R4 PATH1 ran)

  kprep<<<dim3(1048), dim3(256), 0, stream>>>(Wih,b_ih,b_hh,Wt,bt_ih,bt_hh,wp,F1,b1,wsf);
  kprep2<<<dim3(1), dim3(64), 0, stream>>>(DisM, wsf);
  kern_main <<<dim3(256,32), NTHR, 0, stream>>>(li, exs, AngleM, bp, F2, b2,
                                                wsf, con1u, wsf + OFF_SM);
  kern_final<<<dim3(128,32), NTHR, 0, stream>>>(li, labels, ff, bff, fuse1, biasf,
                                                Wout, biasout, a, wsf, con1u, outp);
}